// Round 9
// baseline (70.572 us; speedup 1.0000x reference)
//
#include <hip/hip_runtime.h>

// Problem dims (fixed by harness setup_inputs)
#define NB 4
#define WR 320
#define NH 240
#define WL 320
#define NK 9
#define TW 32                     // = one 128B cache line per staged row
#define NTILES 10
#define ABASE 0                   // A: s in [16,152): 136 rows x 32 floats (128B lines)
#define BBASE 4352                // B: s in [0,16):   16 rows x 16 floats (sub0 only)
#define CBASE 4608                // C: s in [152,168):16 rows x 16 floats (sub1 only)
#define DISPOFF 4864
#define LDSF (DISPOFF + 64)       // 19712 B -> 8 blocks/CU = 32 waves (max)
#define RSTRIDE ((size_t)NH * WL) // 76800 floats
#define NBLK (NB * NTILES * NH)   // 9600
#define NXCD 8

typedef const __attribute__((address_space(1))) void* gas_t;
typedef __attribute__((address_space(3))) void* las_t;

__device__ __forceinline__ void gld16(const float* g, float* l) {
  __builtin_amdgcn_global_load_lds((gas_t)g, (las_t)l, 16, 0, 0);
}
__device__ __forceinline__ void gld4(const float* g, float* l) {
  __builtin_amdgcn_global_load_lds((gas_t)g, (las_t)l, 4, 0, 0);
}

// Band slot s = (j<<L) + 96 - w0. Verified algebra (incl. level-3 8-align
// quantization): sub0 (cols 0..15) uses s in [0,152); sub1 (16..31) uses
// [16,168). Region boundaries 16 and 152 are = 0 mod 8 and pooling spans
// start 8-aligned (96-w0 = 0 mod 32) -> no pooled sum crosses a region.
template <int L>
__device__ __forceinline__ void sample_level(const float* __restrict__ lds,
                                             int lane, int b, int h, int w0,
                                             float* __restrict__ out) {
  const int kpar = lane >> 5;  // k parity (evens / odds)
  const int c = lane & 31;     // column within tile
  const int cl = c & 15;
  const int sbase = 96 - w0;
  const float sc = 1.0f / (float)(1 << L);
  const int Wm1 = (WR >> L) - 1;

  const float dsp = lds[DISPOFF + c];
  const float fidx = ((float)(w0 + c) - dsp) * sc;

  auto pooled = [&](int j) -> float {
    const int s = (j << L) + sbase;
    int a, stride;
    if (s < 16) {            // top taper (sub0 lanes only, by band algebra)
      a = BBASE + s * 16 + cl;
      stride = 16;
    } else if (s < 152) {    // main 128B-line region
      a = ABASE + (s - 16) * 32 + c;
      stride = 32;
    } else {                 // bottom taper (sub1 lanes only)
      a = CBASE + (s - 152) * 16 + cl;
      stride = 16;
    }
    float v = lds[a];
#pragma unroll
    for (int t = 1; t < (1 << L); ++t) v += lds[a + t * stride];
    return v;
  };

#pragma unroll
  for (int m = 0; m < 5; ++m) {
    const int kraw = kpar + 2 * m;
    const int k = min(kraw, 8);  // keep invalid lanes' reads in-band
    const float idx = fminf(fmaxf(fidx + (float)(k - 4), 0.0f), (float)Wm1);
    const int i0 = (int)idx;
    const int i1 = min(i0 + 1, Wm1);
    const float w = idx - (float)i0;
    const float v0 = pooled(i0);
    const float v1 = pooled(i1);
    if (kraw < NK) {  // 2 x 128B contiguous segments per store instr
      out[((size_t)(b * (4 * NK) + L * NK + k) * NH + h) * WL + w0 + c] =
          sc * fmaf(w, v1 - v0, v0);
    }
  }
}

extern "C" __global__ __launch_bounds__(256, 8) void corr_sample_kernel(
    const float* __restrict__ corr, const float* __restrict__ disp,
    float* __restrict__ out) {
  __shared__ float lds0[LDSF];

  // bijective XCD chunking (9600 = 8 x 1200), tile-fastest (as R8)
  const int bid = ((int)blockIdx.x & (NXCD - 1)) * (NBLK / NXCD) +
                  ((int)blockIdx.x >> 3);
  const int tile = bid % NTILES;
  const int rest = bid / NTILES;
  const int h = rest % NH;
  const int b = rest / NH;
  const int w0 = tile * TW;

  const int tid = (int)threadIdx.x;
  const int lane = tid & 63;
  const int wv = tid >> 6;  // wave id == pyramid level

  const size_t cb = (size_t)b * WR * RSTRIDE;
  const size_t hW = (size_t)h * WL;

  // ---- stage: every 128B line touched exactly once (line-exact reads) ----
  // A: 17 instrs x (8 rows x 128 B); B/C: 1 instr x (16 rows x 64 B); +disp.
  // Waves: wv0={A0,4,8,12,16} wv1={A1,5,9,13,B} wv2={A2,6,10,14,C}
  //        wv3={A3,7,11,15,disp} -> 5 instrs each.
  for (int i = wv; i < 17; i += 4) {
    int r = w0 - 80 + 8 * i + (lane >> 3);
    r = min(max(r, 0), WR - 1);  // clamped slots never sampled; L2 dedups
    const float* src =
        corr + cb + (size_t)r * RSTRIDE + hW + w0 + ((lane & 7) << 2);
    gld16(src, &lds0[ABASE + i * 256]);
  }
  if (wv == 1) {  // B: rows [w0-96, w0-80) x cols [w0, w0+16)
    int r = w0 - 96 + (lane >> 2);
    r = min(max(r, 0), WR - 1);
    gld16(corr + cb + (size_t)r * RSTRIDE + hW + w0 + ((lane & 3) << 2),
          &lds0[BBASE]);
  }
  if (wv == 2) {  // C: rows [w0+56, w0+72) x cols [w0+16, w0+32)
    int r = w0 + 56 + (lane >> 2);
    r = min(max(r, 0), WR - 1);
    gld16(corr + cb + (size_t)r * RSTRIDE + hW + w0 + 16 + ((lane & 3) << 2),
          &lds0[CBASE]);
  }
  if (wv == 3) {  // disp: 32 needed floats (lanes 32-63 dup harmlessly)
    gld4(disp + (size_t)b * NH * WL + hW + w0 + (lane & 31), &lds0[DISPOFF]);
  }

  asm volatile("s_waitcnt vmcnt(0)" ::: "memory");
  __syncthreads();

  // ---- sample: wave wv = level ----
  switch (wv) {
    case 0: sample_level<0>(lds0, lane, b, h, w0, out); break;
    case 1: sample_level<1>(lds0, lane, b, h, w0, out); break;
    case 2: sample_level<2>(lds0, lane, b, h, w0, out); break;
    default: sample_level<3>(lds0, lane, b, h, w0, out); break;
  }
}

extern "C" void kernel_launch(void* const* d_in, const int* in_sizes, int n_in,
                              void* d_out, int out_size, void* d_ws,
                              size_t ws_size, hipStream_t stream) {
  const float* corr = (const float*)d_in[0];
  const float* disp = (const float*)d_in[1];
  float* out = (float*)d_out;
  corr_sample_kernel<<<NBLK, 256, 0, stream>>>(corr, disp, out);
}

// Round 10
// 41.428 us; speedup vs baseline: 1.7035x; 1.7035x over previous
//
#include <hip/hip_runtime.h>

// Problem dims (fixed by harness setup_inputs)
#define NB 4
#define WR 320
#define NH 240
#define WL 320
#define NK 9
#define TW 16
#define NTILES 20
#define HH 2                       // h-rows per block (8 blocks/CU residency)
#define SLOTS 152                  // band rows [w0-96, w0+55], exact
#define NI 19                      // staging instrs: 8 slots x 2 h x 64 B each
#define DISPOFF (SLOTS * HH * TW)  // 4864 floats
#define LDSF (DISPOFF + 64)        // + disp (64 floats, half dup)
#define RSTRIDE ((size_t)NH * WL)  // 76800 floats
#define NBLK (NB * NTILES * (NH / HH))  // 9600
#define NXCD 8

typedef const __attribute__((address_space(1))) void* gas_t;
typedef __attribute__((address_space(3))) void* las_t;

__device__ __forceinline__ void gld16(const float* g, float* l) {
  __builtin_amdgcn_global_load_lds((gas_t)g, (las_t)l, 16, 0, 0);
}
__device__ __forceinline__ void gld4(const float* g, float* l) {
  __builtin_amdgcn_global_load_lds((gas_t)g, (las_t)l, 4, 0, 0);
}

// band LDS addr: slot*32 + hh*16 + c; bank = (hh*16+c)%32, slot-independent
// -> kpar pairs alias 2-way = free (m136)
template <int L>
__device__ __forceinline__ float pooledf(const float* p, int j, int sbase,
                                         int hc) {
  const int a = ((j << L) + sbase) * 32 + hc;
  float v = p[a];
#pragma unroll
  for (int t = 1; t < (1 << L); ++t) v += p[a + t * 32];
  return v;
}

template <int L>
__device__ __forceinline__ void sample_level(const float* __restrict__ lds,
                                             int lane, int b, int h0, int w0,
                                             float* __restrict__ out) {
  const int kpar = lane >> 5;      // k parity (evens / odds)
  const int hh = (lane >> 4) & 1;  // h within pair
  const int c = lane & 15;         // column
  const int hc = hh * 16 + c;
  const int sbase = 96 - w0;
  const float sc = 1.0f / (float)(1 << L);
  const int Wm1 = (WR >> L) - 1;

  const float dsp = lds[DISPOFF + hc];
  const float fidx = ((float)(w0 + c) - dsp) * sc;

#pragma unroll
  for (int m = 0; m < 5; ++m) {
    const int kraw = kpar + 2 * m;
    const int k = min(kraw, 8);  // keep invalid lanes' reads in-band
    const float idx = fminf(fmaxf(fidx + (float)(k - 4), 0.0f), (float)Wm1);
    const int i0 = (int)idx;
    const int i1 = min(i0 + 1, Wm1);
    const float w = idx - (float)i0;
    const float v0 = pooledf<L>(lds, i0, sbase, hc);
    const float v1 = pooledf<L>(lds, i1, sbase, hc);
    if (kraw < NK) {
      out[((size_t)(b * (4 * NK) + L * NK + k) * NH + (h0 + hh)) * WL + w0 +
          c] = sc * fmaf(w, v1 - v0, v0);
    }
  }
}

extern "C" __global__ __launch_bounds__(256, 8) void corr_sample_kernel(
    const float* __restrict__ corr, const float* __restrict__ disp,
    float* __restrict__ out) {
  __shared__ float lds0[LDSF];  // 19.3 KB -> 8 blocks/CU = 32 waves (max)

  // bijective XCD chunking (9600 = 8 x 1200), tile-fastest
  const int bid = ((int)blockIdx.x & (NXCD - 1)) * (NBLK / NXCD) +
                  ((int)blockIdx.x >> 3);
  const int tile = bid % NTILES;
  const int rest = bid / NTILES;
  const int hp = rest % (NH / HH);
  const int b = rest / (NH / HH);
  const int w0 = tile * TW;
  const int h0 = hp * HH;

  const int tid = (int)threadIdx.x;
  const int lane = tid & 63;
  const int wv = tid >> 6;  // wave id == pyramid level

  // ---- stage band: 19 instrs, each = 8 slots x 2 h x 64 B ----
  {
    const int ds = lane >> 3;        // slot within 8-group
    const int sh = (lane >> 2) & 1;  // h within pair
    const int c4 = (lane & 3) << 2;  // float col
    const size_t cb = (size_t)b * WR * RSTRIDE;
    for (int g = wv; g < NI; g += 4) {  // waves 0-2: 5 instrs; wave 3: 4
      int rr = w0 - 96 + 8 * g + ds;
      rr = min(max(rr, 0), WR - 1);  // clamped slots never sampled; L2 dedups
      const float* src =
          corr + cb + ((size_t)rr * NH + (h0 + sh)) * WL + w0 + c4;
      gld16(src, &lds0[g * 256]);
    }
    if (wv == 3) {  // wave 3's 5th instr: stage disp (lanes 32-63 dup)
      const float* dsrc = disp + ((size_t)b * NH + (h0 + ((lane >> 4) & 1))) * WL +
                          w0 + (lane & 15);
      gld4(dsrc, &lds0[DISPOFF]);
    }
  }

  asm volatile("s_waitcnt vmcnt(0)" ::: "memory");
  __syncthreads();

  // ---- sample: wave wv = level ----
  switch (wv) {
    case 0: sample_level<0>(lds0, lane, b, h0, w0, out); break;
    case 1: sample_level<1>(lds0, lane, b, h0, w0, out); break;
    case 2: sample_level<2>(lds0, lane, b, h0, w0, out); break;
    default: sample_level<3>(lds0, lane, b, h0, w0, out); break;
  }
}

extern "C" void kernel_launch(void* const* d_in, const int* in_sizes, int n_in,
                              void* d_out, int out_size, void* d_ws,
                              size_t ws_size, hipStream_t stream) {
  const float* corr = (const float*)d_in[0];
  const float* disp = (const float*)d_in[1];
  float* out = (float*)d_out;
  corr_sample_kernel<<<NBLK, 256, 0, stream>>>(corr, disp, out);
}